// Round 9
// baseline (219.226 us; speedup 1.0000x reference)
//
#include <hip/hip_runtime.h>

// GraphConv B=256,N=512,D=6,F=128,MAX_DEG=6.
// R14 post-mortem: 2-resident halves -> 1.8TB/s but +30MB cross-half atom
// re-read -> net +5us. Nine-experiment law: barrier-convoy molecule blocks
// pin at 1.5-1.8 TB/s; only many INDEPENDENT non-convoy blocks exceed 2.3
// (R7 4/CU: 2.3, R11 streaming: 3.0). FETCH(35MB) < kernel reads(73MB) ->
// atoms are L3-resident; the limiter is the L3->CU path under bursty
// barrier-gated issue. R15: kill the convoy. Block = 64 rows x 256 thr
// (4 thr/row, 32 cols in 32 VGPRs). Degree-sort rows (1 barrier pair);
// gather SELF+NBR rows directly from global (L2/L3-hot, per-thread
// sequential 128B segments, sorted -> degree-uniform waves) with ZERO
// barriers and ZERO LDS in the hot loop; one 16KB granule-swizzled LDS
// pack + 1 barrier; MFMA phase B as before. launch_bounds(256,4) ->
// >=4 indep blocks/CU, grid 2048. HBM bytes minimal (gather re-reads are
// L2/L3-side, ~235MB vs 34TB/s L2 agg).

typedef short bf16x8 __attribute__((ext_vector_type(8)));
typedef float f32x4  __attribute__((ext_vector_type(4)));
typedef unsigned short ushort_t;
typedef unsigned int uint_t;

constexpr int Nn = 512;
constexpr int Ff = 128;
constexpr int RB = 64;                          // rows per block

// ws: Wt bf16 [6][128][128] ([d][n][k])
constexpr size_t WS_NEEDED = 196608;

__device__ inline ushort_t f2bf(float f) {      // round-to-nearest-even
    uint_t u = __float_as_uint(f);
    return (ushort_t)((u + 0x7FFFu + ((u >> 16) & 1u)) >> 16);
}

__device__ inline bool detect_is64(const int* edges32) {
    // int64 edges: odd dwords are sign-extension words in {0,-1}.
    int probe = edges32[2 * (threadIdx.x & 63) + 1];
    return __any(probe > 0) == 0;
}

// ---------------- k0: W fp32 [d][k][n] -> Wt bf16 [d][n][k] ----------------
__global__ __launch_bounds__(1024)
void k0_wt(const float* __restrict__ W, ushort_t* __restrict__ Wt) {
    __shared__ float w[128 * 133];              // pad 133: conflict-free transpose
    const int d = blockIdx.x;
    const float* src = W + (size_t)d * 16384;
    #pragma unroll
    for (int i = 0; i < 16; i++) {
        int idx = threadIdx.x + i * 1024;       // [k][n] linear, coalesced read
        w[(idx >> 7) * 133 + (idx & 127)] = src[idx];
    }
    __syncthreads();
    ushort_t* dst = Wt + (size_t)d * 16384;
    #pragma unroll
    for (int i = 0; i < 16; i++) {
        int idx = threadIdx.x + i * 1024;       // [n][k] linear, coalesced write
        dst[idx] = f2bf(w[(idx & 127) * 133 + (idx >> 7)]);
    }
}

// ---------------- fused: 64-row blocks, register gather, no convoy ----------
// summed granule g(k0,row,kq) = k0*(RB*4) + row*4 + (kq ^ (row&3)); 16B each.
__global__ __launch_bounds__(256, 4)
void k_fused(const float* __restrict__ atoms,
             const int*   __restrict__ edges32,
             const ushort_t* __restrict__ Wt,
             const float* __restrict__ bias,
             float* __restrict__ out) {
    const int tid  = threadIdx.x;
    const int row0 = blockIdx.x * RB;           // flat atom-row base
    const int molbase = row0 & ~(Nn - 1);       // molecule start (RB divides Nn)
    const bool is64 = detect_is64(edges32);     // convergent

    __shared__ __attribute__((aligned(16))) ushort_t summed[RB * 128];  // 16384 B
    __shared__ ushort_t nbp[RB * 6];            // 768 B packed nbr ids
    __shared__ ushort_t rlist[RB];              // degree-sorted local rows
    __shared__ int hist[8];

    const int pr = tid >> 2, h = tid & 3;       // row / col-quarter (32 floats)

    // --- phase 0: degrees, ranks, sorted row list (one barrier pair) ---
    if (tid < 8) hist[tid] = 0;
    __syncthreads();
    int deg = 0;
    {
        int e[6];
        const size_t eb = (size_t)(row0 + pr) * 6;
        if (is64) {
            #pragma unroll
            for (int j = 0; j < 6; j++) e[j] = edges32[(eb + j) * 2];
        } else {
            #pragma unroll
            for (int j = 0; j < 6; j++) e[j] = edges32[eb + j];
        }
        #pragma unroll
        for (int j = 0; j < 6; j++) deg += (e[j] >= 0) ? 1 : 0;
        if (deg > 5) deg = 5;                   // spec: deg<=5; guard
        if (h == 0) {
            #pragma unroll
            for (int j = 0; j < 6; j++)
                nbp[pr * 6 + j] = (ushort_t)(e[j] >= 0 ? e[j] : 0xFFFF);
        }
    }
    int rk = 0;
    if (h == 0) rk = atomicAdd(&hist[deg], 1);
    __syncthreads();
    int cnts[6], cbase[6];
    {
        int a = 0;
        #pragma unroll
        for (int d = 0; d < 6; d++) { cnts[d] = hist[d]; cbase[d] = a; a += cnts[d]; }
    }
    if (h == 0) rlist[cbase[deg] + rk] = (ushort_t)pr;
    __syncthreads();

    // --- gather: register-resident, straight from L2/L3, barrier-free ---
    const int lr = rlist[pr];                   // my sorted row (degree-uniform wave)
    float4 acc[8];                              // 32 floats: cols [h*32, h*32+32)
    {
        const float4* sp = (const float4*)(atoms + (size_t)(row0 + lr) * Ff) + h * 8;
        #pragma unroll
        for (int q = 0; q < 8; q++) acc[q] = sp[q];
    }
    #pragma unroll
    for (int j = 0; j < 6; j++) {
        int e = nbp[lr * 6 + j];
        if (e != 0xFFFF) {                      // sorted -> near-uniform exec
            const float4* np = (const float4*)(atoms + (size_t)(molbase + e) * Ff) + h * 8;
            #pragma unroll
            for (int q = 0; q < 8; q++) {
                float4 v = np[q];
                acc[q].x += v.x; acc[q].y += v.y; acc[q].z += v.z; acc[q].w += v.w;
            }
        }
    }
    // pack 32 f32 -> 4 swizzled 16B granules (k0 = h)
    #pragma unroll
    for (int q2 = 0; q2 < 4; q2++) {
        uint4 o;
        o.x = (uint_t)f2bf(acc[2 * q2].x)     | ((uint_t)f2bf(acc[2 * q2].y) << 16);
        o.y = (uint_t)f2bf(acc[2 * q2].z)     | ((uint_t)f2bf(acc[2 * q2].w) << 16);
        o.z = (uint_t)f2bf(acc[2 * q2 + 1].x) | ((uint_t)f2bf(acc[2 * q2 + 1].y) << 16);
        o.w = (uint_t)f2bf(acc[2 * q2 + 1].z) | ((uint_t)f2bf(acc[2 * q2 + 1].w) << 16);
        int g = h * (RB * 4) + lr * 4 + (q2 ^ (lr & 3));
        *(uint4*)&summed[g * 8] = o;
    }
    __syncthreads();                            // summed complete

    // --- phase B: flattened MFMA items over the 64 rows ---
    const int lane = tid & 63, wid = tid >> 6;  // 4 waves
    const int kq = lane >> 4, ml = lane & 15;

    int Tp[7];
    {
        int a = 0;
        #pragma unroll
        for (int d = 0; d < 6; d++) { Tp[d] = a; a += ((cnts[d] + 15) >> 4) * 4; }
        Tp[6] = a;
    }
    const int items = Tp[6];

    for (int it = wid; it < items; it += 4) {
        int d = 0;
        #pragma unroll
        for (int dd = 1; dd < 6; dd++) if (it >= Tp[dd]) d = dd;
        const int loc = it - Tp[d];
        const int ti = loc >> 2, ci = loc & 3;  // row-tile, col-pair
        const int cn = cnts[d], cb = cbase[d];

        int lidx = ti * 16 + ml;
        int cl = (lidx < cn) ? lidx : cn - 1;   // clamp; stores masked
        int row = rlist[cb + cl];               // local row
        bf16x8 af[4];                           // A: m=ml, k=kq*8+k0*32
        #pragma unroll
        for (int k0 = 0; k0 < 4; k0++)
            af[k0] = *(const bf16x8*)&summed[(k0 * (RB * 4) + row * 4 + (kq ^ (row & 3))) * 8];
        int orw[4];                             // C/D rows: kq*4+reg
        #pragma unroll
        for (int r = 0; r < 4; r++) {
            int li = ti * 16 + kq * 4 + r;
            orw[r] = (li < cn) ? (int)rlist[cb + li] : -1;
        }
        const ushort_t* wg = Wt + (size_t)d * 16384;
        #pragma unroll
        for (int n2 = 0; n2 < 2; n2++) {
            const int nt = ci * 2 + n2;
            bf16x8 bfr[4];                      // B: n=ml, k=kq*8+k0*32 (global, L2-hot)
            #pragma unroll
            for (int k0 = 0; k0 < 4; k0++)
                bfr[k0] = *(const bf16x8*)&wg[(nt * 16 + ml) * 128 + k0 * 32 + kq * 8];
            f32x4 c = {0.f, 0.f, 0.f, 0.f};
            #pragma unroll
            for (int k0 = 0; k0 < 4; k0++)
                c = __builtin_amdgcn_mfma_f32_16x16x32_bf16(af[k0], bfr[k0], c, 0, 0, 0);
            const int col = nt * 16 + ml;
            const float bc = bias[d * Ff + col];
            #pragma unroll
            for (int r = 0; r < 4; r++) {
                if (orw[r] >= 0) {
                    float v = c[r] + bc;
                    out[(size_t)(row0 + orw[r]) * Ff + col] = v > 0.f ? v : 0.f;
                }
            }
        }
    }
}

// ---------------- fallback (round-1 kernel) if ws too small ----------------
__global__ __launch_bounds__(128, 2)
void graphconv_fallback(const float* __restrict__ atoms,
                        const int* __restrict__ edges_raw,
                        const float* __restrict__ W,
                        const float* __restrict__ bias,
                        float* __restrict__ out) {
    const int tid = threadIdx.x;
    const int d = blockIdx.x % 6;
    const int k = blockIdx.x / 6;
    const int a0 = k * 256;
    __shared__ int eds[256 * 6];
    __shared__ int list[256];
    __shared__ int cnt;
    __shared__ float sv[2][Ff];
    bool is64;
    { int v = edges_raw[2 * (tid & 63) + 1]; is64 = (__ballot(v > 0) == 0ull); }
    if (!is64) { for (int i = tid; i < 256 * 6; i += 128) eds[i] = edges_raw[a0 * 6 + i]; }
    else       { for (int i = tid; i < 256 * 6; i += 128) eds[i] = edges_raw[2 * (a0 * 6 + i)]; }
    if (tid == 0) cnt = 0;
    __syncthreads();
    for (int i = tid; i < 256; i += 128) {
        int deg = 0;
        #pragma unroll
        for (int j = 0; j < 6; j++) deg += (eds[i * 6 + j] != -1) ? 1 : 0;
        if (deg == d) { int p = atomicAdd(&cnt, 1); list[p] = i; }
    }
    float Wreg[Ff];
    { const float* Wd = W + (size_t)d * Ff * Ff;
      #pragma unroll
      for (int f = 0; f < Ff; f++) Wreg[f] = Wd[f * Ff + tid]; }
    const float breg = bias[d * Ff + tid];
    __syncthreads();
    const int n = cnt;
    const float* batch_atoms = atoms + (size_t)(a0 / Nn) * Nn * Ff;
    const int row0 = a0 % Nn;
    for (int ii = 0; ii < n; ii++) {
        const int i = list[ii];
        float s = batch_atoms[(row0 + i) * Ff + tid];
        #pragma unroll
        for (int j = 0; j < 6; j++) {
            int e = eds[i * 6 + j];
            if (e != -1) s += batch_atoms[e * Ff + tid];
        }
        float* buf = sv[ii & 1];
        buf[tid] = s;
        __syncthreads();
        float acc = breg;
        const float4* sv4 = (const float4*)buf;
        #pragma unroll
        for (int fc = 0; fc < Ff / 4; fc++) {
            float4 x = sv4[fc];
            acc = fmaf(x.x, Wreg[4 * fc + 0], acc);
            acc = fmaf(x.y, Wreg[4 * fc + 1], acc);
            acc = fmaf(x.z, Wreg[4 * fc + 2], acc);
            acc = fmaf(x.w, Wreg[4 * fc + 3], acc);
        }
        out[(size_t)(a0 + i) * Ff + tid] = fmaxf(acc, 0.0f);
    }
}

extern "C" void kernel_launch(void* const* d_in, const int* in_sizes, int n_in,
                              void* d_out, int out_size, void* d_ws, size_t ws_size,
                              hipStream_t stream) {
    const float* atoms = (const float*)d_in[0];
    const int*   edges = (const int*)d_in[1];
    const float* W     = (const float*)d_in[2];
    const float* bias  = (const float*)d_in[3];
    float*       outp  = (float*)d_out;

    if (ws_size >= WS_NEEDED) {
        ushort_t* Wt = (ushort_t*)d_ws;
        k0_wt<<<6, 1024, 0, stream>>>(W, Wt);
        k_fused<<<(256 * Nn) / RB, 256, 0, stream>>>(atoms, edges, Wt, bias, outp);
    } else {
        graphconv_fallback<<<3072, 128, 0, stream>>>(atoms, edges, W, bias, outp);
    }
}